// Round 2
// baseline (1807.905 us; speedup 1.0000x reference)
//
#include <hip/hip_runtime.h>

#define HID    128
#define GATES  512      // 4*HID
#define EMB    64
#define TSTEPS 1024
#define BATCH  512
#define VOCAB  50257
#define NCLS   28

typedef __attribute__((ext_vector_type(8))) short short8;   // 8 bf16 = 4 VGPRs
typedef __attribute__((ext_vector_type(4))) float f32x4;

static __device__ __forceinline__ float bf2f(unsigned short u){
  union { unsigned int i; float f; } v; v.i = ((unsigned int)u) << 16; return v.f;
}
static __device__ __forceinline__ unsigned short f2bf(float f){
  union { float ff; unsigned int i; } v; v.ff = f;
  unsigned int x = v.i;
  x += 0x7fffu + ((x >> 16) & 1u);   // round-to-nearest-even
  return (unsigned short)(x >> 16);
}
static __device__ __forceinline__ float sigf(float x){
  float e = __builtin_amdgcn_exp2f(-1.44269504f * x);
  return __builtin_amdgcn_rcpf(1.f + e);
}
static __device__ __forceinline__ float tanhf_fast(float x){
  float xx = fminf(fmaxf(x, -16.f), 16.f);
  float e = __builtin_amdgcn_exp2f(-2.88539008f * xx);   // exp(-2x)
  return (1.f - e) * __builtin_amdgcn_rcpf(1.f + e);
}

// ---------------------------------------------------------------------------
// Phase 1: proj[v][g] = sum_e emb[v][e]*w_ih[g][e] + b_ih[g] + b_hh[g]
// f32 inputs; split-bf16 (hi+lo) MFMA -> f32-accurate result.
// [V x 64] @ [64 x 512]; 16 vocab rows per block, K=64 = 2 chunks of 32.
// ---------------------------------------------------------------------------
template<bool STORE_F32>
__global__ __launch_bounds__(256) void emb_proj_kernel(
    const float* __restrict__ emb,     // [V][64]
    const float* __restrict__ w_ih,    // [512][64]
    const float* __restrict__ b_ih,    // [512]
    const float* __restrict__ b_hh,    // [512]
    void* __restrict__ proj_raw)       // [V][512] f32 or bf16
{
  int wave = threadIdx.x >> 6;
  int lane = threadIdx.x & 63;
  int n = lane & 15;           // A row / B col / C col
  int q = lane >> 4;           // quad
  long v0 = (long)blockIdx.x * 16;

  // A-frags: emb rows; A[m=lane&15][k = ch*32 + q*8 + j], split hi/lo
  long vrow = v0 + n; if (vrow >= VOCAB) vrow = VOCAB - 1;
  const float* er = emb + vrow * EMB;
  short8 ahi[2], alo[2];
  #pragma unroll
  for (int ch = 0; ch < 2; ++ch){
    #pragma unroll
    for (int j = 0; j < 8; ++j){
      float xv = er[ch * 32 + q * 8 + j];
      unsigned short h = f2bf(xv);
      float r = xv - bf2f(h);
      ahi[ch][j] = (short)h;
      alo[ch][j] = (short)f2bf(r);
    }
  }

  #pragma unroll
  for (int i = 0; i < 8; ++i){
    int g0 = (wave * 8 + i) * 16;
    // B-frags: B[k][n] = w_ih[g0+n][k], split hi/lo
    const float* wr = w_ih + (long)(g0 + n) * EMB;
    short8 bhi[2], blo[2];
    #pragma unroll
    for (int ch = 0; ch < 2; ++ch){
      #pragma unroll
      for (int j = 0; j < 8; ++j){
        float xv = wr[ch * 32 + q * 8 + j];
        unsigned short h = f2bf(xv);
        float r = xv - bf2f(h);
        bhi[ch][j] = (short)h;
        blo[ch][j] = (short)f2bf(r);
      }
    }
    float bias = b_ih[g0 + n] + b_hh[g0 + n];
    f32x4 acc = {bias, bias, bias, bias};   // C col = n -> same bias all rows
    #pragma unroll
    for (int ch = 0; ch < 2; ++ch){
      acc = __builtin_amdgcn_mfma_f32_16x16x32_bf16(ahi[ch], bhi[ch], acc, 0, 0, 0);
      acc = __builtin_amdgcn_mfma_f32_16x16x32_bf16(ahi[ch], blo[ch], acc, 0, 0, 0);
      acc = __builtin_amdgcn_mfma_f32_16x16x32_bf16(alo[ch], bhi[ch], acc, 0, 0, 0);
    }
    // C/D: row = 4*q + r (vocab row), col = n (gate)
    #pragma unroll
    for (int r = 0; r < 4; ++r){
      long row = v0 + q * 4 + r;
      if (row < VOCAB){
        if (STORE_F32)
          ((float*)proj_raw)[row * GATES + g0 + n] = acc[r];
        else
          ((unsigned short*)proj_raw)[row * GATES + g0 + n] = f2bf(acc[r]);
      }
    }
  }
}

// ---------------------------------------------------------------------------
// Phase 2: LSTM recurrence + final linear.
// 256 blocks x 256 threads; block owns 2 batch rows.
// gates^T = w_hh @ h^T via 16x16x32 MFMA: A = w_hh (bf16, static in regs),
// B = h (bf16 in LDS). Cols 0..1 of each MFMA are the real batch rows.
// ---------------------------------------------------------------------------
template<bool GXF32>
__global__ __launch_bounds__(256, 1) void lstm_kernel(
    const int* __restrict__ x,         // [512][1024] int32
    const float* __restrict__ w_hh,    // [512][128] f32
    const void* __restrict__ proj_raw, // [V][512] f32 or bf16 (bias folded)
    const float* __restrict__ w_lin,   // [28][128] f32
    const float* __restrict__ b_lin,   // [28] f32
    float* __restrict__ out)           // [512][28] f32
{
  __shared__ short h_lds[2][HID];              // bf16 bits
  __shared__ float gates_lds[2][GATES + 4];    // f32, padded row

  int tid = threadIdx.x;
  int wave = tid >> 6;
  int lane = tid & 63;
  int n = lane & 15;           // MFMA col
  int q = lane >> 4;           // quad
  int r0 = blockIdx.x * 2;

  // --- preload A-frags: w_hh rows (f32 -> bf16) ------------------------
  // tile (t,s): gate base m0 = t*128 + wave*32 + s*16; A[m=n][k=ch*32+q*8+j]
  short8 A[4][2][4];
  #pragma unroll
  for (int t = 0; t < 4; ++t)
    #pragma unroll
    for (int s = 0; s < 2; ++s){
      int m0 = t * 128 + wave * 32 + s * 16;
      const float* wr = w_hh + (long)(m0 + n) * HID;
      #pragma unroll
      for (int ch = 0; ch < 4; ++ch)
        #pragma unroll
        for (int j = 0; j < 8; ++j)
          A[t][s][ch][j] = (short)f2bf(wr[ch * 32 + q * 8 + j]);
    }

  for (int i = tid; i < 2 * HID; i += 256) ((short*)h_lds)[i] = 0;
  float c_state = 0.f;
  int b_nl = tid >> 7;                 // 0..1
  int hcol = tid & 127;

  bool gxact = (n < 2);                // cols 0,1 are the real batch rows
  int xrow = r0 + (n & 1);
  f32x4 gxf[4][2];
  uint2  gxb[4][2];

  // gx prefetch (step 0)
  {
    int tok = x[xrow * TSTEPS + 0];
    if (gxact){
      #pragma unroll
      for (int t = 0; t < 4; ++t)
        #pragma unroll
        for (int s = 0; s < 2; ++s){
          int m0 = t * 128 + wave * 32 + s * 16;
          if constexpr (GXF32){
            const float* pr = (const float*)proj_raw + (long)tok * GATES;
            gxf[t][s] = *(const f32x4*)(pr + m0 + q * 4);
          } else {
            const unsigned int* pr =
                (const unsigned int*)((const unsigned short*)proj_raw + (long)tok * GATES);
            gxb[t][s] = *(const uint2*)(pr + (m0 + q * 4) / 2);
          }
        }
    }
  }
  __syncthreads();

  for (int step = 0; step < TSTEPS; ++step){
    // B-frags: B[k][n] = h[row n&1][k], k = ch*32 + q*8 + j
    short8 Bf[4];
    #pragma unroll
    for (int ch = 0; ch < 4; ++ch)
      Bf[ch] = *(const short8*)(&h_lds[n & 1][ch * 32 + q * 8]);

    // acc init from gx (C layout: row = gate m0+4q+r, col n = batch)
    f32x4 acc[4][2];
    #pragma unroll
    for (int t = 0; t < 4; ++t)
      #pragma unroll
      for (int s = 0; s < 2; ++s){
        if (gxact){
          if constexpr (GXF32){
            acc[t][s] = gxf[t][s];
          } else {
            unsigned int d0 = gxb[t][s].x, d1 = gxb[t][s].y;
            union { unsigned int i; float f; } u0, u1, u2, u3;
            u0.i = d0 << 16; u1.i = d0 & 0xffff0000u;
            u2.i = d1 << 16; u3.i = d1 & 0xffff0000u;
            acc[t][s] = (f32x4){u0.f, u1.f, u2.f, u3.f};
          }
        } else {
          acc[t][s] = (f32x4){0.f, 0.f, 0.f, 0.f};
        }
      }

    // prefetch next step's gx (hidden under MFMAs)
    if (step + 1 < TSTEPS){
      int tok = x[xrow * TSTEPS + step + 1];
      if (gxact){
        #pragma unroll
        for (int t = 0; t < 4; ++t)
          #pragma unroll
          for (int s = 0; s < 2; ++s){
            int m0 = t * 128 + wave * 32 + s * 16;
            if constexpr (GXF32){
              const float* pr = (const float*)proj_raw + (long)tok * GATES;
              gxf[t][s] = *(const f32x4*)(pr + m0 + q * 4);
            } else {
              const unsigned int* pr =
                  (const unsigned int*)((const unsigned short*)proj_raw + (long)tok * GATES);
              gxb[t][s] = *(const uint2*)(pr + (m0 + q * 4) / 2);
            }
          }
      }
    }

    // MFMAs: 8 tiles x 4 K-chunks
    #pragma unroll
    for (int ch = 0; ch < 4; ++ch)
      #pragma unroll
      for (int t = 0; t < 4; ++t)
        #pragma unroll
        for (int s = 0; s < 2; ++s)
          acc[t][s] = __builtin_amdgcn_mfma_f32_16x16x32_bf16(
              A[t][s][ch], Bf[ch], acc[t][s], 0, 0, 0);

    // write owned gate columns to LDS (f32x4 = gates m0+4q .. +3, batch n)
    if (gxact){
      #pragma unroll
      for (int t = 0; t < 4; ++t)
        #pragma unroll
        for (int s = 0; s < 2; ++s){
          int m0 = t * 128 + wave * 32 + s * 16;
          *(f32x4*)(&gates_lds[n][m0 + q * 4]) = acc[t][s];
        }
    }
    __syncthreads();

    // nonlinearity: one (b, hcol) cell per thread
    {
      float gi = gates_lds[b_nl][hcol];
      float gf = gates_lds[b_nl][128 + hcol];
      float gg = gates_lds[b_nl][256 + hcol];
      float go = gates_lds[b_nl][384 + hcol];
      float si = sigf(gi), sf = sigf(gf), so = sigf(go);
      float tg = tanhf_fast(gg);
      c_state = sf * c_state + si * tg;
      float h = so * tanhf_fast(c_state);
      h_lds[b_nl][hcol] = (short)f2bf(h);
    }
    __syncthreads();
  }

  // --- final linear: out[b][j] = h[b] . w_lin[j] + b_lin[j] (f32) ------
  if (tid < 2 * NCLS){
    int b = tid / NCLS, j = tid % NCLS;
    float acc = b_lin[j];
    const float* wl = w_lin + (long)j * HID;
    #pragma unroll 4
    for (int k = 0; k < HID; ++k)
      acc += bf2f((unsigned short)h_lds[b][k]) * wl[k];
    out[(r0 + b) * NCLS + j] = acc;
  }
}

// ---------------------------------------------------------------------------
extern "C" void kernel_launch(void* const* d_in, const int* in_sizes, int n_in,
                              void* d_out, int out_size, void* d_ws, size_t ws_size,
                              hipStream_t stream)
{
  const int*   x     = (const int*)d_in[0];
  const float* emb   = (const float*)d_in[1];
  const float* w_ih  = (const float*)d_in[2];
  const float* w_hh  = (const float*)d_in[3];
  const float* b_ih  = (const float*)d_in[4];
  const float* b_hh  = (const float*)d_in[5];
  const float* w_lin = (const float*)d_in[6];
  const float* b_lin = (const float*)d_in[7];
  float*       out   = (float*)d_out;

  size_t need_f32 = (size_t)VOCAB * GATES * sizeof(float);   // ~103 MB
  int vblocks = (VOCAB + 15) / 16;   // 3142

  if (ws_size >= need_f32){
    emb_proj_kernel<true><<<dim3(vblocks), dim3(256), 0, stream>>>(
        emb, w_ih, b_ih, b_hh, d_ws);
    lstm_kernel<true><<<dim3(BATCH / 2), dim3(256), 0, stream>>>(
        x, w_hh, d_ws, w_lin, b_lin, out);
  } else {
    emb_proj_kernel<false><<<dim3(vblocks), dim3(256), 0, stream>>>(
        emb, w_ih, b_ih, b_hh, d_ws);
    lstm_kernel<false><<<dim3(BATCH / 2), dim3(256), 0, stream>>>(
        x, w_hh, d_ws, w_lin, b_lin, out);
  }
}

// Round 3
// 1120.045 us; speedup vs baseline: 1.6141x; 1.6141x over previous
//
#include <hip/hip_runtime.h>

#define HID    128
#define GATES  512      // 4*HID
#define EMB    64
#define TSTEPS 1024
#define BATCH  512
#define VOCAB  50257
#define NCLS   28

typedef __attribute__((ext_vector_type(8))) short short8;   // 8 bf16 = 4 VGPRs
typedef __attribute__((ext_vector_type(4))) float f32x4;

static __device__ __forceinline__ float bf2f(unsigned short u){
  union { unsigned int i; float f; } v; v.i = ((unsigned int)u) << 16; return v.f;
}
static __device__ __forceinline__ unsigned short f2bf(float f){
  union { float ff; unsigned int i; } v; v.ff = f;
  unsigned int x = v.i;
  x += 0x7fffu + ((x >> 16) & 1u);   // round-to-nearest-even
  return (unsigned short)(x >> 16);
}
static __device__ __forceinline__ float sigf(float x){
  float e = __builtin_amdgcn_exp2f(-1.44269504f * x);
  return __builtin_amdgcn_rcpf(1.f + e);
}
static __device__ __forceinline__ float tanhf_fast(float x){
  float xx = fminf(fmaxf(x, -16.f), 16.f);
  float e = __builtin_amdgcn_exp2f(-2.88539008f * xx);   // exp(-2x)
  return (1.f - e) * __builtin_amdgcn_rcpf(1.f + e);
}

// ---------------------------------------------------------------------------
// Phase 1: proj[v][g] = sum_e emb[v][e]*w_ih[g][e] + b_ih[g] + b_hh[g]
// f32 inputs; split-bf16 (hi+lo) MFMA -> f32-accurate. Unchanged from R2.
// ---------------------------------------------------------------------------
template<bool STORE_F32>
__global__ __launch_bounds__(256) void emb_proj_kernel(
    const float* __restrict__ emb,     // [V][64]
    const float* __restrict__ w_ih,    // [512][64]
    const float* __restrict__ b_ih,    // [512]
    const float* __restrict__ b_hh,    // [512]
    void* __restrict__ proj_raw)       // [V][512] f32 or bf16
{
  int wave = threadIdx.x >> 6;
  int lane = threadIdx.x & 63;
  int n = lane & 15;
  int q = lane >> 4;
  long v0 = (long)blockIdx.x * 16;

  long vrow = v0 + n; if (vrow >= VOCAB) vrow = VOCAB - 1;
  const float* er = emb + vrow * EMB;
  short8 ahi[2], alo[2];
  #pragma unroll
  for (int ch = 0; ch < 2; ++ch){
    #pragma unroll
    for (int j = 0; j < 8; ++j){
      float xv = er[ch * 32 + q * 8 + j];
      unsigned short h = f2bf(xv);
      float r = xv - bf2f(h);
      ahi[ch][j] = (short)h;
      alo[ch][j] = (short)f2bf(r);
    }
  }

  #pragma unroll
  for (int i = 0; i < 8; ++i){
    int g0 = (wave * 8 + i) * 16;
    const float* wr = w_ih + (long)(g0 + n) * EMB;
    short8 bhi[2], blo[2];
    #pragma unroll
    for (int ch = 0; ch < 2; ++ch){
      #pragma unroll
      for (int j = 0; j < 8; ++j){
        float xv = wr[ch * 32 + q * 8 + j];
        unsigned short h = f2bf(xv);
        float r = xv - bf2f(h);
        bhi[ch][j] = (short)h;
        blo[ch][j] = (short)f2bf(r);
      }
    }
    float bias = b_ih[g0 + n] + b_hh[g0 + n];
    f32x4 acc = {bias, bias, bias, bias};
    #pragma unroll
    for (int ch = 0; ch < 2; ++ch){
      acc = __builtin_amdgcn_mfma_f32_16x16x32_bf16(ahi[ch], bhi[ch], acc, 0, 0, 0);
      acc = __builtin_amdgcn_mfma_f32_16x16x32_bf16(ahi[ch], blo[ch], acc, 0, 0, 0);
      acc = __builtin_amdgcn_mfma_f32_16x16x32_bf16(alo[ch], bhi[ch], acc, 0, 0, 0);
    }
    #pragma unroll
    for (int r = 0; r < 4; ++r){
      long row = v0 + q * 4 + r;
      if (row < VOCAB){
        if (STORE_F32)
          ((float*)proj_raw)[row * GATES + g0 + n] = acc[r];
        else
          ((unsigned short*)proj_raw)[row * GATES + g0 + n] = f2bf(acc[r]);
      }
    }
  }
}

// ---------------------------------------------------------------------------
// Phase 2: LSTM recurrence + final linear.
// 512 blocks x 256 threads, 1 batch row per block -> 2 blocks/CU
// (two independent recurrences interleave per SIMD = latency hiding).
// gates = w_hh @ h via 16x16x32 MFMA, col 0 only. A = w_hh static in regs.
// Per-wave gate redistribution through wave-private LDS (no barrier);
// h double-buffered in LDS -> ONE __syncthreads per step.
// ---------------------------------------------------------------------------
template<bool GXF32>
__global__ __launch_bounds__(256, 2) void lstm_kernel(
    const int* __restrict__ x,         // [512][1024] int32
    const float* __restrict__ w_hh,    // [512][128] f32
    const void* __restrict__ proj_raw, // [V][512] f32 or bf16 (bias folded)
    const float* __restrict__ w_lin,   // [28][128] f32
    const float* __restrict__ b_lin,   // [28] f32
    float* __restrict__ out)           // [512][28] f32
{
  __shared__ int   tok_lds[TSTEPS];        // this row's tokens (4 KB)
  __shared__ short h_lds[2][HID];          // double-buffered h (bf16 bits)
  __shared__ float wg_lds[4][4 * 32];      // per-wave gates [wave][t*32+c]

  int tid  = threadIdx.x;
  int wave = tid >> 6;
  int lane = tid & 63;
  int n = lane & 15;           // MFMA col
  int q = lane >> 4;           // quad
  int r0 = blockIdx.x;         // batch row

  // --- preload this row's tokens into LDS ------------------------------
  for (int i = tid; i < TSTEPS; i += 256)
    tok_lds[i] = x[(long)r0 * TSTEPS + i];

  // --- preload A-frags: w_hh rows (f32 -> bf16), 8 tiles per wave -------
  // tile (t,s): gate base m0 = t*128 + wave*32 + s*16; A[m=n][k=ch*32+q*8+j]
  short8 A[4][2][4];
  #pragma unroll
  for (int t = 0; t < 4; ++t)
    #pragma unroll
    for (int s = 0; s < 2; ++s){
      int m0 = t * 128 + wave * 32 + s * 16;
      const float* wr = w_hh + (long)(m0 + n) * HID;
      #pragma unroll
      for (int ch = 0; ch < 4; ++ch)
        #pragma unroll
        for (int j = 0; j < 8; ++j)
          A[t][s][ch][j] = (short)f2bf(wr[ch * 32 + q * 8 + j]);
    }

  // zero h buffers (h0 = 0)
  for (int i = tid; i < 2 * HID; i += 256) ((short*)h_lds)[i] = 0;

  float c_state = 0.f;               // lane l<32: cell for hcol wave*32+l
  bool  nlact = (lane < 32);
  bool  gxact = (n == 0);            // lanes 0,16,32,48 carry col 0

  f32x4 gxf[4][2];
  uint2 gxb[4][2];
  #pragma unroll
  for (int t = 0; t < 4; ++t)
    #pragma unroll
    for (int s = 0; s < 2; ++s){
      gxf[t][s] = (f32x4){0.f, 0.f, 0.f, 0.f};
      gxb[t][s] = (uint2){0u, 0u};
    }

  __syncthreads();   // tokens + h zeros visible

  // gx prefetch for step 0 (immediate-offset loads off one base pointer)
  {
    int tok = tok_lds[0];
    if (gxact){
      if constexpr (GXF32){
        const float* pr = (const float*)proj_raw + (long)tok * GATES + wave * 32 + q * 4;
        #pragma unroll
        for (int t = 0; t < 4; ++t)
          #pragma unroll
          for (int s = 0; s < 2; ++s)
            gxf[t][s] = *(const f32x4*)(pr + t * 128 + s * 16);
      } else {
        const unsigned short* pr =
            (const unsigned short*)proj_raw + (long)tok * GATES + wave * 32 + q * 4;
        #pragma unroll
        for (int t = 0; t < 4; ++t)
          #pragma unroll
          for (int s = 0; s < 2; ++s)
            gxb[t][s] = *(const uint2*)(pr + t * 128 + s * 16);
      }
    }
  }

  for (int step = 0; step < TSTEPS; ++step){
    int rb = step & 1;

    // B-frags: B[k][0] = h[k], k = ch*32 + q*8 + j (16-lane broadcast reads)
    short8 Bf[4];
    #pragma unroll
    for (int ch = 0; ch < 4; ++ch)
      Bf[ch] = *(const short8*)(&h_lds[rb][ch * 32 + q * 8]);

    // acc init from gx (unconditional; cols != 0 are garbage-but-unused)
    f32x4 acc[4][2];
    #pragma unroll
    for (int t = 0; t < 4; ++t)
      #pragma unroll
      for (int s = 0; s < 2; ++s){
        if constexpr (GXF32){
          acc[t][s] = gxf[t][s];
        } else {
          unsigned int d0 = gxb[t][s].x, d1 = gxb[t][s].y;
          union { unsigned int i; float f; } u0, u1, u2, u3;
          u0.i = d0 << 16; u1.i = d0 & 0xffff0000u;
          u2.i = d1 << 16; u3.i = d1 & 0xffff0000u;
          acc[t][s] = (f32x4){u0.f, u1.f, u2.f, u3.f};
        }
      }

    // prefetch next step's gx (token already in LDS; hidden under MFMAs)
    if (step + 1 < TSTEPS){
      int tok = tok_lds[step + 1];
      if (gxact){
        if constexpr (GXF32){
          const float* pr = (const float*)proj_raw + (long)tok * GATES + wave * 32 + q * 4;
          #pragma unroll
          for (int t = 0; t < 4; ++t)
            #pragma unroll
            for (int s = 0; s < 2; ++s)
              gxf[t][s] = *(const f32x4*)(pr + t * 128 + s * 16);
        } else {
          const unsigned short* pr =
              (const unsigned short*)proj_raw + (long)tok * GATES + wave * 32 + q * 4;
          #pragma unroll
          for (int t = 0; t < 4; ++t)
            #pragma unroll
            for (int s = 0; s < 2; ++s)
              gxb[t][s] = *(const uint2*)(pr + t * 128 + s * 16);
        }
      }
    }

    // MFMAs: 8 tiles x 4 K-chunks
    #pragma unroll
    for (int ch = 0; ch < 4; ++ch)
      #pragma unroll
      for (int t = 0; t < 4; ++t)
        #pragma unroll
        for (int s = 0; s < 2; ++s)
          acc[t][s] = __builtin_amdgcn_mfma_f32_16x16x32_bf16(
              A[t][s][ch], Bf[ch], acc[t][s], 0, 0, 0);

    // gates -> wave-private LDS (no barrier; same wave consumes).
    // lane 16q holds C rows q*4+r of col 0 = gates m0 + q*4 + r.
    if (gxact){
      #pragma unroll
      for (int t = 0; t < 4; ++t)
        #pragma unroll
        for (int s = 0; s < 2; ++s)
          *(f32x4*)(&wg_lds[wave][t * 32 + s * 16 + q * 4]) = acc[t][s];
    }

    // nonlinearity: lanes 0..31 handle the wave's 32 hcols
    if (nlact){
      int l = lane;
      float gi = wg_lds[wave][l];
      float gf = wg_lds[wave][32 + l];
      float gg = wg_lds[wave][64 + l];
      float go = wg_lds[wave][96 + l];
      float si = sigf(gi), sf = sigf(gf), so = sigf(go);
      float tg = tanhf_fast(gg);
      c_state = sf * c_state + si * tg;
      float h = so * tanhf_fast(c_state);
      h_lds[rb ^ 1][wave * 32 + l] = (short)f2bf(h);
    }
    __syncthreads();   // h exchange (the only barrier per step)
  }

  // --- final linear: out[r0][j] = h . w_lin[j] + b_lin[j] --------------
  // TSTEPS even -> final h is in h_lds[0]
  if (tid < NCLS){
    int j = tid;
    float acc = b_lin[j];
    const float* wl = w_lin + (long)j * HID;
    #pragma unroll 4
    for (int k = 0; k < HID; ++k)
      acc += bf2f((unsigned short)h_lds[0][k]) * wl[k];
    out[(long)r0 * NCLS + j] = acc;
  }
}

// ---------------------------------------------------------------------------
extern "C" void kernel_launch(void* const* d_in, const int* in_sizes, int n_in,
                              void* d_out, int out_size, void* d_ws, size_t ws_size,
                              hipStream_t stream)
{
  const int*   x     = (const int*)d_in[0];
  const float* emb   = (const float*)d_in[1];
  const float* w_ih  = (const float*)d_in[2];
  const float* w_hh  = (const float*)d_in[3];
  const float* b_ih  = (const float*)d_in[4];
  const float* b_hh  = (const float*)d_in[5];
  const float* w_lin = (const float*)d_in[6];
  const float* b_lin = (const float*)d_in[7];
  float*       out   = (float*)d_out;

  size_t need_f32 = (size_t)VOCAB * GATES * sizeof(float);   // ~103 MB
  int vblocks = (VOCAB + 15) / 16;   // 3142

  if (ws_size >= need_f32){
    emb_proj_kernel<true><<<dim3(vblocks), dim3(256), 0, stream>>>(
        emb, w_ih, b_ih, b_hh, d_ws);
    lstm_kernel<true><<<dim3(BATCH), dim3(256), 0, stream>>>(
        x, w_hh, d_ws, w_lin, b_lin, out);
  } else {
    emb_proj_kernel<false><<<dim3(vblocks), dim3(256), 0, stream>>>(
        emb, w_ih, b_ih, b_hh, d_ws);
    lstm_kernel<false><<<dim3(BATCH), dim3(256), 0, stream>>>(
        x, w_hh, d_ws, w_lin, b_lin, out);
  }
}